// Round 1
// baseline (3643.077 us; speedup 1.0000x reference)
//
#include <hip/hip_runtime.h>
#include <math.h>

#define D 16
#define NPARTS 1024
#define BLOCK 256
#define APT 2   // atoms per thread

__global__ __launch_bounds__(BLOCK) void nodes_mlp_kernel(
    const float* __restrict__ x,       // [N,16]
    const float* __restrict__ charge,  // [1024]
    const float* __restrict__ W1, const float* __restrict__ b1,
    const float* __restrict__ W2, const float* __restrict__ b2,
    const float* __restrict__ W3, const float* __restrict__ b3,
    const int*   __restrict__ part,    // [N]
    float* __restrict__ out,           // [N,16]
    int n)
{
    __shared__ float sW[3][D * D];
    __shared__ float sb[3][D];
    __shared__ float sq[NPARTS];

    const int t = threadIdx.x;

    // Stage weights / biases / charge table into LDS
    for (int i = t; i < D * D; i += BLOCK) {
        sW[0][i] = W1[i];
        sW[1][i] = W2[i];
        sW[2][i] = W3[i];
    }
    if (t < D) {
        sb[0][t] = b1[t];
        sb[1][t] = b2[t];
        sb[2][t] = b3[t];
    }
    for (int i = t; i < NPARTS; i += BLOCK) sq[i] = charge[i];
    __syncthreads();

    const long long base = (long long)blockIdx.x * (BLOCK * APT);

    long long aidx[APT];
    bool alive[APT];
    int  prt[APT];
    float h[APT][D];

    // Load inputs (float4-vectorized, coalesced at 64B lane stride),
    // and kick off the part-index loads early.
#pragma unroll
    for (int a = 0; a < APT; ++a) {
        aidx[a] = base + (long long)a * BLOCK + t;
        alive[a] = aidx[a] < (long long)n;
        prt[a] = alive[a] ? part[aidx[a]] : 0;
        if (alive[a]) {
            const float4* xp = (const float4*)(x + aidx[a] * D);
#pragma unroll
            for (int j = 0; j < 4; ++j) ((float4*)&h[a][0])[j] = xp[j];
        } else {
#pragma unroll
            for (int k = 0; k < D; ++k) h[a][k] = 0.0f;
        }
    }

    // 3 layers of y = x @ W^T + b, ELU
#pragma unroll
    for (int L = 0; L < 3; ++L) {
        float o[APT][D];
#pragma unroll
        for (int j = 0; j < D; ++j) {
            const float4* wr = (const float4*)&sW[L][j * D];
            float4 w0 = wr[0], w1 = wr[1], w2 = wr[2], w3 = wr[3];
            float bj = sb[L][j];
#pragma unroll
            for (int a = 0; a < APT; ++a) {
                float acc = bj;
                acc += h[a][0]  * w0.x + h[a][1]  * w0.y + h[a][2]  * w0.z + h[a][3]  * w0.w;
                acc += h[a][4]  * w1.x + h[a][5]  * w1.y + h[a][6]  * w1.z + h[a][7]  * w1.w;
                acc += h[a][8]  * w2.x + h[a][9]  * w2.y + h[a][10] * w2.z + h[a][11] * w2.w;
                acc += h[a][12] * w3.x + h[a][13] * w3.y + h[a][14] * w3.z + h[a][15] * w3.w;
                o[a][j] = acc;
            }
        }
        // ELU, write back into h
#pragma unroll
        for (int a = 0; a < APT; ++a) {
#pragma unroll
            for (int j = 0; j < D; ++j) {
                float v = o[a][j];
                h[a][j] = (v > 0.0f) ? v : (__expf(v) - 1.0f);
            }
        }
    }

    // Epilogue: + (float)part + charge[part], store float4
#pragma unroll
    for (int a = 0; a < APT; ++a) {
        if (alive[a]) {
            float add = (float)prt[a] + sq[prt[a]];
            float4* op = (float4*)(out + aidx[a] * D);
#pragma unroll
            for (int j = 0; j < 4; ++j) {
                float4 v = ((float4*)&h[a][0])[j];
                v.x += add; v.y += add; v.z += add; v.w += add;
                op[j] = v;
            }
        }
    }
}

extern "C" void kernel_launch(void* const* d_in, const int* in_sizes, int n_in,
                              void* d_out, int out_size, void* d_ws, size_t ws_size,
                              hipStream_t stream) {
    const float* x      = (const float*)d_in[0];
    const float* charge = (const float*)d_in[1];
    const float* W1     = (const float*)d_in[2];
    const float* b1     = (const float*)d_in[3];
    const float* W2     = (const float*)d_in[4];
    const float* b2     = (const float*)d_in[5];
    const float* W3     = (const float*)d_in[6];
    const float* b3     = (const float*)d_in[7];
    const int*   part   = (const int*)d_in[8];
    float* out = (float*)d_out;

    const int n = in_sizes[8];                 // number of atoms
    const int atoms_per_block = BLOCK * APT;   // 512
    const int grid = (n + atoms_per_block - 1) / atoms_per_block;

    nodes_mlp_kernel<<<grid, BLOCK, 0, stream>>>(
        x, charge, W1, b1, W2, b2, W3, b3, part, out, n);
}

// Round 2
// 511.364 us; speedup vs baseline: 7.1242x; 7.1242x over previous
//
#include <hip/hip_runtime.h>
#include <math.h>

#define D 16
#define NPARTS 1024
#define BLOCK 256

__global__ __launch_bounds__(BLOCK, 4) void nodes_mlp_kernel(
    const float* __restrict__ x,       // [N,16]
    const float* __restrict__ charge,  // [1024]
    const float* __restrict__ W1, const float* __restrict__ b1,
    const float* __restrict__ W2, const float* __restrict__ b2,
    const float* __restrict__ W3, const float* __restrict__ b3,
    const int*   __restrict__ part,    // [N]
    float* __restrict__ out,           // [N,16]
    int n)
{
    // Only the gathered table lives in LDS (4 KB). Weights/biases are read
    // with wave-uniform addresses -> compiler emits s_load (SGPR operands,
    // no LDS traffic, no per-lane VMEM).
    __shared__ float sq[NPARTS];
    const int t = threadIdx.x;
    for (int i = t; i < NPARTS; i += BLOCK) sq[i] = charge[i];
    __syncthreads();

    const long long idx = (long long)blockIdx.x * BLOCK + t;
    if (idx >= (long long)n) return;

    const int prt = part[idx];

    // Load 16 features via float4 registers; NO address-of on locals
    // (round-1 lesson: (float4*)&h[] casts forced h/o into scratch ->
    // 10 GB of spill traffic).
    const float4* xp = (const float4*)(x + idx * D);
    float4 v0 = xp[0], v1 = xp[1], v2 = xp[2], v3 = xp[3];

    float h[D];
    h[0]  = v0.x; h[1]  = v0.y; h[2]  = v0.z; h[3]  = v0.w;
    h[4]  = v1.x; h[5]  = v1.y; h[6]  = v1.z; h[7]  = v1.w;
    h[8]  = v2.x; h[9]  = v2.y; h[10] = v2.z; h[11] = v2.w;
    h[12] = v3.x; h[13] = v3.y; h[14] = v3.z; h[15] = v3.w;

    const float* Ws[3] = {W1, W2, W3};
    const float* bs[3] = {b1, b2, b3};

#pragma unroll
    for (int L = 0; L < 3; ++L) {
        const float* __restrict__ W = Ws[L];
        const float* __restrict__ b = bs[L];
        float o[D];
#pragma unroll
        for (int j = 0; j < D; ++j) {
            float acc = b[j];
#pragma unroll
            for (int k = 0; k < D; ++k) {
                acc += h[k] * W[j * D + k];
            }
            o[j] = acc;
        }
        // ELU
#pragma unroll
        for (int j = 0; j < D; ++j) {
            float v = o[j];
            h[j] = (v > 0.0f) ? v : (__expf(v) - 1.0f);
        }
    }

    // Epilogue: + (float)part + charge[part]
    const float add = (float)prt + sq[prt];

    float4 r0 = make_float4(h[0]  + add, h[1]  + add, h[2]  + add, h[3]  + add);
    float4 r1 = make_float4(h[4]  + add, h[5]  + add, h[6]  + add, h[7]  + add);
    float4 r2 = make_float4(h[8]  + add, h[9]  + add, h[10] + add, h[11] + add);
    float4 r3 = make_float4(h[12] + add, h[13] + add, h[14] + add, h[15] + add);

    float4* op = (float4*)(out + idx * D);
    op[0] = r0; op[1] = r1; op[2] = r2; op[3] = r3;
}

extern "C" void kernel_launch(void* const* d_in, const int* in_sizes, int n_in,
                              void* d_out, int out_size, void* d_ws, size_t ws_size,
                              hipStream_t stream) {
    const float* x      = (const float*)d_in[0];
    const float* charge = (const float*)d_in[1];
    const float* W1     = (const float*)d_in[2];
    const float* b1     = (const float*)d_in[3];
    const float* W2     = (const float*)d_in[4];
    const float* b2     = (const float*)d_in[5];
    const float* W3     = (const float*)d_in[6];
    const float* b3     = (const float*)d_in[7];
    const int*   part   = (const int*)d_in[8];
    float* out = (float*)d_out;

    const int n = in_sizes[8];                 // number of atoms (4,000,000)
    const int grid = (n + BLOCK - 1) / BLOCK;  // 15625 blocks, no tail at 4M

    nodes_mlp_kernel<<<grid, BLOCK, 0, stream>>>(
        x, charge, W1, b1, W2, b2, W3, b3, part, out, n);
}